// Round 6
// baseline (198.201 us; speedup 1.0000x reference)
//
#include <hip/hip_runtime.h>

typedef float f32x4 __attribute__((ext_vector_type(4)));
typedef __bf16 bf16x8 __attribute__((ext_vector_type(8)));
typedef unsigned short us8 __attribute__((ext_vector_type(8)));
typedef unsigned short us4 __attribute__((ext_vector_type(4)));

#define QSCALE 11.541560327111707f   // 8 * log2(e) -> softmax in exp2 domain
#define NEG_INF (-__builtin_inff())

__device__ __forceinline__ float fexp2(float x) {
    return __builtin_amdgcn_exp2f(x);
}
__device__ __forceinline__ unsigned short f2bf(float x) {   // round-nearest
    unsigned u = __builtin_bit_cast(unsigned, x);
    u += 0x7fffu + ((u >> 16) & 1u);
    return (unsigned short)(u >> 16);
}
__device__ __forceinline__ float bf2f(unsigned short h) {
    unsigned u = ((unsigned)h) << 16;
    return __builtin_bit_cast(float, u);
}
__device__ __forceinline__ unsigned short bftrunc(float x) { // truncate
    return (unsigned short)(__builtin_bit_cast(unsigned, x) >> 16);
}
__device__ __forceinline__ f32x4 mfma16(us8 a, us8 b, f32x4 c) {
    return __builtin_amdgcn_mfma_f32_16x16x32_bf16(
        __builtin_bit_cast(bf16x8, a), __builtin_bit_cast(bf16x8, b), c, 0, 0, 0);
}

// ---------------- Kernel 0: W transpose + split (RN split) ----------------
__global__ __launch_bounds__(256) void wprep_kernel(
    const float* __restrict__ Wq, const float* __restrict__ Wk,
    const float* __restrict__ Wv,
    unsigned short* __restrict__ Wthi, unsigned short* __restrict__ Wtlo)
{
    __shared__ __align__(16) float Ls[64][68];
    const int g = blockIdx.x >> 4;
    const int k0 = (blockIdx.x & 15) << 6;
    const float* W = (g == 0) ? Wq : (g == 1) ? Wk : Wv;
    const int t = threadIdx.x;
#pragma unroll
    for (int u = 0; u < 4; ++u) {
        int idx = t + (u << 8);
        int row = idx >> 4, c4 = (idx & 15) << 2;
        *(float4*)&Ls[row][c4] = *(const float4*)&W[(size_t)(k0 + row) * 64 + c4];
    }
    __syncthreads();
    const int h = t >> 2, kk0 = (t & 3) << 4;
    size_t base = (size_t)((g << 6) + h) * 1024 + k0 + kk0;
#pragma unroll
    for (int c = 0; c < 4; ++c) {
        us4 hv, lv;
#pragma unroll
        for (int i = 0; i < 4; ++i) {
            float x = Ls[kk0 + (c << 2) + i][h];
            unsigned short hh = f2bf(x);
            hv[i] = hh;
            lv[i] = f2bf(x - bf2f(hh));
        }
        *(us4*)&Wthi[base + (c << 2)] = hv;
        *(us4*)&Wtlo[base + (c << 2)] = lv;
    }
}

// ---------------- Kernel 1: fused QKV projection (barrier-free) -----------
// 512 blocks x 32 rows, 4 waves each owning 32x48 (full 192 cols per block
// -> X read ONCE). No LDS / no __syncthreads in the K-loop: A-frags direct
// from global X (trunc-split in regs, L1 dedups 4-wave overlap), B-frags
// direct per-lane 16B loads from L2-resident W. X prefetched 1 iter ahead;
// W-lo consumed only in the last MFMA third (L2 latency slack).
__global__ __launch_bounds__(256, 2) void qkv_kernel(
    const float* __restrict__ X,
    const unsigned short* __restrict__ Wthi,
    const unsigned short* __restrict__ Wtlo,
    unsigned short* __restrict__ Qhi, unsigned short* __restrict__ Qlo,
    unsigned short* __restrict__ Khi, unsigned short* __restrict__ Klo,
    unsigned short* __restrict__ Vthi)
{
    __shared__ __align__(16) unsigned short Vx[4 * 320];   // V-transpose scratch

    const int t = threadIdx.x;
    const int w = t >> 6, l = t & 63, lm = l & 15, lg = (l >> 4) & 3;
    const int m0 = blockIdx.x << 5;
    const int wcol = w * 48;

    // per-lane base pointers
    const float* xp[2];          // [mt] -> row m0+mt*16+lm, k base lg*8
#pragma unroll
    for (int mt = 0; mt < 2; ++mt)
        xp[mt] = X + (size_t)(m0 + (mt << 4) + lm) * 1024 + (lg << 3);
    const unsigned short* whp[3];  // [ct] -> W row wcol+ct*16+lm
    const unsigned short* wlp[3];
#pragma unroll
    for (int ct = 0; ct < 3; ++ct) {
        size_t off = (size_t)(wcol + (ct << 4) + lm) * 1024 + (lg << 3);
        whp[ct] = Wthi + off;
        wlp[ct] = Wtlo + off;
    }

    f32x4 acc[2][3];
#pragma unroll
    for (int i = 0; i < 2; ++i)
#pragma unroll
        for (int j = 0; j < 3; ++j) acc[i][j] = (f32x4){0.f, 0.f, 0.f, 0.f};

    // X prefetch regs: [mt][kc][half-of-8]
    float4 xr[2][2][2];
#pragma unroll
    for (int mt = 0; mt < 2; ++mt)
#pragma unroll
        for (int kc = 0; kc < 2; ++kc) {
            xr[mt][kc][0] = *(const float4*)(xp[mt] + (kc << 5));
            xr[mt][kc][1] = *(const float4*)(xp[mt] + (kc << 5) + 4);
        }

    for (int k = 0; k < 16; ++k) {
        const int k0 = k << 6;
        // B loads for this iter (hi first, lo later-consumed)
        us8 bh[3][2], blv[3][2];
#pragma unroll
        for (int ct = 0; ct < 3; ++ct)
#pragma unroll
            for (int kc = 0; kc < 2; ++kc) {
                bh[ct][kc]  = *(const us8*)(whp[ct] + k0 + (kc << 5));
                blv[ct][kc] = *(const us8*)(wlp[ct] + k0 + (kc << 5));
            }
        // convert current X regs -> A frags (trunc-hi split)
        us8 ah[2][2], al[2][2];
#pragma unroll
        for (int mt = 0; mt < 2; ++mt)
#pragma unroll
            for (int kc = 0; kc < 2; ++kc) {
                float xf[8];
                xf[0] = xr[mt][kc][0].x; xf[1] = xr[mt][kc][0].y;
                xf[2] = xr[mt][kc][0].z; xf[3] = xr[mt][kc][0].w;
                xf[4] = xr[mt][kc][1].x; xf[5] = xr[mt][kc][1].y;
                xf[6] = xr[mt][kc][1].z; xf[7] = xr[mt][kc][1].w;
                us8 h, lo;
#pragma unroll
                for (int e = 0; e < 8; ++e) {
                    unsigned u = __builtin_bit_cast(unsigned, xf[e]);
                    h[e] = (unsigned short)(u >> 16);
                    lo[e] = bftrunc(xf[e] - __builtin_bit_cast(float, u & 0xffff0000u));
                }
                ah[mt][kc] = h; al[mt][kc] = lo;
            }
        // prefetch next-iter X
        if (k < 15) {
            const int kn = (k + 1) << 6;
#pragma unroll
            for (int mt = 0; mt < 2; ++mt)
#pragma unroll
                for (int kc = 0; kc < 2; ++kc) {
                    xr[mt][kc][0] = *(const float4*)(xp[mt] + kn + (kc << 5));
                    xr[mt][kc][1] = *(const float4*)(xp[mt] + kn + (kc << 5) + 4);
                }
        }
        // MFMAs: hi*hi and lo*hi first (W-lo latency slack), then hi*lo
#pragma unroll
        for (int kc = 0; kc < 2; ++kc)
#pragma unroll
            for (int mt = 0; mt < 2; ++mt)
#pragma unroll
                for (int ct = 0; ct < 3; ++ct) {
                    acc[mt][ct] = mfma16(ah[mt][kc], bh[ct][kc], acc[mt][ct]);
                    acc[mt][ct] = mfma16(al[mt][kc], bh[ct][kc], acc[mt][ct]);
                }
#pragma unroll
        for (int kc = 0; kc < 2; ++kc)
#pragma unroll
            for (int mt = 0; mt < 2; ++mt)
#pragma unroll
                for (int ct = 0; ct < 3; ++ct)
                    acc[mt][ct] = mfma16(ah[mt][kc], blv[ct][kc], acc[mt][ct]);
    }

    // epilogue: trunc-split stores; Q pre-scaled; V transposed via Vx
#pragma unroll
    for (int mt = 0; mt < 2; ++mt) {
#pragma unroll
        for (int ct = 0; ct < 3; ++ct) {
            const int gc = wcol + (ct << 4);
            if (gc < 128) {
                unsigned short* Dh = (gc < 64) ? Qhi : Khi;
                unsigned short* Dl = (gc < 64) ? Qlo : Klo;
                const float sc = (gc < 64) ? QSCALE : 1.0f;
                const int colb = (gc & 63) + lm;
#pragma unroll
                for (int r = 0; r < 4; ++r) {
                    int row = m0 + (mt << 4) + (lg << 2) + r;
                    float x = acc[mt][ct][r] * sc;
                    unsigned u = __builtin_bit_cast(unsigned, x);
                    size_t o = (size_t)row * 64 + colb;
                    Dh[o] = (unsigned short)(u >> 16);
                    Dl[o] = bftrunc(x - __builtin_bit_cast(float, u & 0xffff0000u));
                }
            } else {
                // V: 16x16 transpose via wave-local LDS
#pragma unroll
                for (int r = 0; r < 4; ++r)
                    Vx[w * 320 + lm * 20 + (lg << 2) + r] = bftrunc(acc[mt][ct][r]);
                __asm__ volatile("" ::: "memory");
                const int h0 = gc - 128;
                const int tb = m0 + (mt << 4);
                const int bb = tb >> 11;
                const int tl = (tb & 2047) + ((l & 3) << 2);
                const int hh2 = h0 + (l >> 2);
                us4 vv = *(const us4*)&Vx[w * 320 + (l >> 2) * 20 + ((l & 3) << 2)];
                *(us4*)&Vthi[(size_t)((bb << 6) + hh2) * 2048 + tl] = vv;
                __asm__ volatile("" ::: "memory");
            }
        }
    }
}

// ---------------- Kernel 2: causal flash attention ----------------
// 512 blocks = (b = blockIdx&7 -> XCD-pinned batch, 32-row q-tile heavy-
// first). 4 waves = 4 key-parities, ZERO barriers in the K-loop (K/V frags
// direct from global, L2-resident). S^T layout: lane = q-row -> softmax
// reduce = 15 local ops + 2 shuffles. exp2 domain. 4-way merge at end.
__global__ __launch_bounds__(256, 2) void attn_kernel(
    const unsigned short* __restrict__ Qhi, const unsigned short* __restrict__ Qlo,
    const unsigned short* __restrict__ Khi, const unsigned short* __restrict__ Klo,
    const unsigned short* __restrict__ Vthi,
    float* __restrict__ O)
{
    __shared__ __align__(16) unsigned char smem[33792];
    unsigned short* PS = (unsigned short*)smem;     // [4][32][72] us (loop phase)
    float* FO = (float*)smem;                       // [4][32][64] f32 (merge phase)
    float* FM = (float*)(smem + 32768);             // [4][32]
    float* FL = FM + 128;

    const int t = threadIdx.x;
    const int w = t >> 6, l = t & 63, lm = l & 15, lg = (l >> 4) & 3;
    const int b = blockIdx.x & 7;
    const int qp = 63 - (blockIdx.x >> 3);          // heavy tiles first
    const int nk = (qp >> 1) + 1;                   // 64-key tiles needed
    const int q0 = qp << 5;
    const size_t brow = (size_t)b << 11;

    // Q fragments pinned (B-operand: lane=qrow, k=lg*8+j)
    us8 qh[2][2], ql[2][2];
#pragma unroll
    for (int nt = 0; nt < 2; ++nt)
#pragma unroll
        for (int kc = 0; kc < 2; ++kc) {
            size_t off = (brow + q0 + (nt << 4) + lm) * 64 + (kc << 5) + (lg << 3);
            qh[nt][kc] = *(const us8*)&Qhi[off];
            ql[nt][kc] = *(const us8*)&Qlo[off];
        }

    f32x4 o_acc[2][4];
#pragma unroll
    for (int nt = 0; nt < 2; ++nt)
#pragma unroll
        for (int ct = 0; ct < 4; ++ct) o_acc[nt][ct] = (f32x4){0.f, 0.f, 0.f, 0.f};
    float m_r[2] = {NEG_INF, NEG_INF}, l_r[2] = {0.f, 0.f};
    unsigned short* ps = PS + w * 2304;             // wave-local 32x72

    for (int j = w; j < nk; j += 4) {
        const int kk0 = j << 6;
        us8 kh[4][2], klo[4][2];
#pragma unroll
        for (int mt = 0; mt < 4; ++mt)
#pragma unroll
            for (int kc = 0; kc < 2; ++kc) {
                size_t off = (brow + kk0 + (mt << 4) + lm) * 64 + (kc << 5) + (lg << 3);
                kh[mt][kc] = *(const us8*)&Khi[off];
                klo[mt][kc] = *(const us8*)&Klo[off];
            }
        // S^T = K Q^T (split-bf16)
        f32x4 s[4][2];
#pragma unroll
        for (int mt = 0; mt < 4; ++mt)
#pragma unroll
            for (int nt = 0; nt < 2; ++nt) s[mt][nt] = (f32x4){0.f, 0.f, 0.f, 0.f};
#pragma unroll
        for (int kc = 0; kc < 2; ++kc)
#pragma unroll
            for (int mt = 0; mt < 4; ++mt)
#pragma unroll
                for (int nt = 0; nt < 2; ++nt) {
                    s[mt][nt] = mfma16(kh[mt][kc], qh[nt][kc], s[mt][nt]);
                    s[mt][nt] = mfma16(klo[mt][kc], qh[nt][kc], s[mt][nt]);
                    s[mt][nt] = mfma16(kh[mt][kc], ql[nt][kc], s[mt][nt]);
                }
        // V loads issued here: latency hides under softmax VALU
        us8 vh[4][2];
#pragma unroll
        for (int ct = 0; ct < 4; ++ct)
#pragma unroll
            for (int kc = 0; kc < 2; ++kc) {
                size_t off = ((size_t)(b << 6) + (ct << 4) + lm) * 2048
                           + kk0 + (kc << 5) + (lg << 3);
                vh[ct][kc] = *(const us8*)&Vthi[off];
            }
        // online softmax (exp2 domain), lane owns row q0+nt*16+lm, 16 keys
        float alz[2];
#pragma unroll
        for (int nt = 0; nt < 2; ++nt) {
            const int qr = q0 + (nt << 4) + lm;
            float sv[16];
            if ((kk0 + 63) <= (q0 + (nt << 4))) {
#pragma unroll
                for (int mt = 0; mt < 4; ++mt)
#pragma unroll
                    for (int r = 0; r < 4; ++r) sv[(mt << 2) + r] = s[mt][nt][r];
            } else {
#pragma unroll
                for (int mt = 0; mt < 4; ++mt)
#pragma unroll
                    for (int r = 0; r < 4; ++r) {
                        const int key = kk0 + (mt << 4) + (lg << 2) + r;
                        sv[(mt << 2) + r] = (key <= qr) ? s[mt][nt][r] : NEG_INF;
                    }
            }
            float t8[8];
#pragma unroll
            for (int i = 0; i < 8; ++i) t8[i] = fmaxf(sv[i], sv[i + 8]);
#pragma unroll
            for (int i = 0; i < 4; ++i) t8[i] = fmaxf(t8[i], t8[i + 4]);
            float mx = fmaxf(fmaxf(t8[0], t8[1]), fmaxf(t8[2], t8[3]));
            mx = fmaxf(mx, __shfl_xor(mx, 16));
            mx = fmaxf(mx, __shfl_xor(mx, 32));
            const float mn = fmaxf(m_r[nt], mx);
            alz[nt] = fexp2(m_r[nt] - mn);
            m_r[nt] = mn;
            float p[16];
#pragma unroll
            for (int i = 0; i < 16; ++i) p[i] = fexp2(sv[i] - mn);
#pragma unroll
            for (int mt = 0; mt < 4; ++mt) {
                us4 pk;
#pragma unroll
                for (int r = 0; r < 4; ++r) pk[r] = bftrunc(p[(mt << 2) + r]);
                *(us4*)&ps[((nt << 4) + lm) * 72 + (mt << 4) + (lg << 2)] = pk;
            }
            float s8[8];
#pragma unroll
            for (int i = 0; i < 8; ++i) s8[i] = p[i] + p[i + 8];
#pragma unroll
            for (int i = 0; i < 4; ++i) s8[i] = s8[i] + s8[i + 4];
            float rs = (s8[0] + s8[1]) + (s8[2] + s8[3]);
            rs += __shfl_xor(rs, 16);
            rs += __shfl_xor(rs, 32);
            l_r[nt] = l_r[nt] * alz[nt] + rs;
        }
        __asm__ volatile("" ::: "memory");   // P write -> read, same wave
        // rescale O (alz lives at lane=row; fetch via shuffle)
#pragma unroll
        for (int nt = 0; nt < 2; ++nt)
#pragma unroll
            for (int r = 0; r < 4; ++r) {
                const float av = __shfl(alz[nt], (lg << 2) + r);
#pragma unroll
                for (int ct = 0; ct < 4; ++ct) o_acc[nt][ct][r] *= av;
            }
        // O += P V
#pragma unroll
        for (int nt = 0; nt < 2; ++nt)
#pragma unroll
            for (int kc = 0; kc < 2; ++kc) {
                us8 pa = *(const us8*)&ps[((nt << 4) + lm) * 72 + (kc << 5) + (lg << 3)];
#pragma unroll
                for (int ct = 0; ct < 4; ++ct)
                    o_acc[nt][ct] = mfma16(pa, vh[ct][kc], o_acc[nt][ct]);
            }
    }

    // ---- 4-way key-parity merge ----
    __syncthreads();                         // all PS use done before FO alias
#pragma unroll
    for (int nt = 0; nt < 2; ++nt)
#pragma unroll
        for (int ct = 0; ct < 4; ++ct)
#pragma unroll
            for (int r = 0; r < 4; ++r)
                FO[(w << 11) + (((nt << 4) + (lg << 2) + r) << 6) + (ct << 4) + lm]
                    = o_acc[nt][ct][r];
    if (l < 16) {
        FM[(w << 5) + lm] = m_r[0]; FM[(w << 5) + 16 + lm] = m_r[1];
        FL[(w << 5) + lm] = l_r[0]; FL[(w << 5) + 16 + lm] = l_r[1];
    }
    __syncthreads();
    const int jr = t >> 3;                   // row 0..31
    const int cg = (t & 7) << 3;             // col base
    float m0v = FM[jr], m1v = FM[32 + jr], m2v = FM[64 + jr], m3v = FM[96 + jr];
    float mm = fmaxf(fmaxf(m0v, m1v), fmaxf(m2v, m3v));
    float a0 = fexp2(m0v - mm), a1 = fexp2(m1v - mm);
    float a2 = fexp2(m2v - mm), a3 = fexp2(m3v - mm);
    float L = a0 * FL[jr] + a1 * FL[32 + jr] + a2 * FL[64 + jr] + a3 * FL[96 + jr];
    float inv = 1.0f / L;
    float ov[8];
#pragma unroll
    for (int c = 0; c < 8; ++c)
        ov[c] = a0 * FO[(jr << 6) + cg + c] + a1 * FO[2048 + (jr << 6) + cg + c]
              + a2 * FO[4096 + (jr << 6) + cg + c] + a3 * FO[6144 + (jr << 6) + cg + c];
    float4 o1 = {ov[0] * inv, ov[1] * inv, ov[2] * inv, ov[3] * inv};
    float4 o2 = {ov[4] * inv, ov[5] * inv, ov[6] * inv, ov[7] * inv};
    float* op = O + (brow + q0 + jr) * 64 + cg;
    *(float4*)op = o1;
    *(float4*)(op + 4) = o2;
}

extern "C" void kernel_launch(void* const* d_in, const int* in_sizes, int n_in,
                              void* d_out, int out_size, void* d_ws, size_t ws_size,
                              hipStream_t stream) {
    const float* X  = (const float*)d_in[0];
    const float* Wq = (const float*)d_in[1];
    const float* Wk = (const float*)d_in[2];
    const float* Wv = (const float*)d_in[3];
    unsigned short* ws = (unsigned short*)d_ws;
    const size_t SZ = (size_t)16384 * 64;
    unsigned short* Qhi  = ws;
    unsigned short* Qlo  = ws + SZ;
    unsigned short* Khi  = ws + 2 * SZ;
    unsigned short* Klo  = ws + 3 * SZ;
    unsigned short* Vthi = ws + 4 * SZ;
    unsigned short* Wthi = ws + 5 * SZ;
    unsigned short* Wtlo = Wthi + 192 * 1024;

    wprep_kernel<<<48, 256, 0, stream>>>(Wq, Wk, Wv, Wthi, Wtlo);
    qkv_kernel<<<512, 256, 0, stream>>>(X, Wthi, Wtlo,
                                        Qhi, Qlo, Khi, Klo, Vthi);
    attn_kernel<<<512, 256, 0, stream>>>(Qhi, Qlo, Khi, Klo, Vthi, (float*)d_out);
}

// Round 7
// 184.738 us; speedup vs baseline: 1.0729x; 1.0729x over previous
//
#include <hip/hip_runtime.h>

typedef float f32x4 __attribute__((ext_vector_type(4)));
typedef __bf16 bf16x8 __attribute__((ext_vector_type(8)));
typedef unsigned short us8 __attribute__((ext_vector_type(8)));
typedef unsigned short us4 __attribute__((ext_vector_type(4)));

#define QSCALE 11.541560327111707f   // 8 * log2(e) -> softmax in exp2 domain
#define NEG_INF (-__builtin_inff())

__device__ __forceinline__ float fexp2(float x) {
    return __builtin_amdgcn_exp2f(x);
}
__device__ __forceinline__ unsigned short f2bf(float x) {   // round-nearest
    unsigned u = __builtin_bit_cast(unsigned, x);
    u += 0x7fffu + ((u >> 16) & 1u);
    return (unsigned short)(u >> 16);
}
__device__ __forceinline__ float bf2f(unsigned short h) {
    unsigned u = ((unsigned)h) << 16;
    return __builtin_bit_cast(float, u);
}
__device__ __forceinline__ unsigned short bftrunc(float x) { // truncate
    return (unsigned short)(__builtin_bit_cast(unsigned, x) >> 16);
}
__device__ __forceinline__ f32x4 mfma16(us8 a, us8 b, f32x4 c) {
    return __builtin_amdgcn_mfma_f32_16x16x32_bf16(
        __builtin_bit_cast(bf16x8, a), __builtin_bit_cast(bf16x8, b), c, 0, 0, 0);
}
__device__ __forceinline__ void glds16(const unsigned short* g, unsigned short* l) {
    __builtin_amdgcn_global_load_lds(
        (const __attribute__((address_space(1))) unsigned int*)g,
        (__attribute__((address_space(3))) unsigned int*)l, 16, 0, 0);
}

// ---------------- Kernel 0: W transpose + split (RN split) ----------------
__global__ __launch_bounds__(256) void wprep_kernel(
    const float* __restrict__ Wq, const float* __restrict__ Wk,
    const float* __restrict__ Wv,
    unsigned short* __restrict__ Wthi, unsigned short* __restrict__ Wtlo)
{
    __shared__ __align__(16) float Ls[64][68];
    const int g = blockIdx.x >> 4;
    const int k0 = (blockIdx.x & 15) << 6;
    const float* W = (g == 0) ? Wq : (g == 1) ? Wk : Wv;
    const int t = threadIdx.x;
#pragma unroll
    for (int u = 0; u < 4; ++u) {
        int idx = t + (u << 8);
        int row = idx >> 4, c4 = (idx & 15) << 2;
        *(float4*)&Ls[row][c4] = *(const float4*)&W[(size_t)(k0 + row) * 64 + c4];
    }
    __syncthreads();
    const int h = t >> 2, kk0 = (t & 3) << 4;
    size_t base = (size_t)((g << 6) + h) * 1024 + k0 + kk0;
#pragma unroll
    for (int c = 0; c < 4; ++c) {
        us4 hv, lv;
#pragma unroll
        for (int i = 0; i < 4; ++i) {
            float x = Ls[kk0 + (c << 2) + i][h];
            unsigned short hh = f2bf(x);
            hv[i] = hh;
            lv[i] = f2bf(x - bf2f(hh));
        }
        *(us4*)&Wthi[base + (c << 2)] = hv;
        *(us4*)&Wtlo[base + (c << 2)] = lv;
    }
}

// ---------------- Kernel 1: fused QKV projection ----------------
// R5 structure (glds16 W-hi double-buffer + LDS X + direct-global W-lo),
// tile shrunk to 32 rows x 96 cols, grid (512,2)=1024 blocks -> 3+ blocks/CU
// so barrier vmcnt-drains are filled by other resident blocks' MFMAs.
__global__ __launch_bounds__(256, 3) void qkv_kernel(
    const float* __restrict__ X,
    const unsigned short* __restrict__ Wthi,
    const unsigned short* __restrict__ Wtlo,
    unsigned short* __restrict__ Qhi, unsigned short* __restrict__ Qlo,
    unsigned short* __restrict__ Khi, unsigned short* __restrict__ Klo,
    unsigned short* __restrict__ Vthi)
{
    __shared__ __align__(16) unsigned short sm[17664];  // 34.5 KB
    unsigned short* Xh = sm;                 // 32x64 swizzled (2048)
    unsigned short* Xl = sm + 2048;          // 2048
    unsigned short* Wh = sm + 4096;          // 2 bufs x 6144 (96x64 swizzled)
    unsigned short* Vx = sm + 16384;         // 4x16x20 transpose scratch

    const int t = threadIdx.x;
    const int w = t >> 6, l = t & 63, lm = l & 15, lg = (l >> 4) & 3;
    const int wq = w >> 1, wc = w & 1;       // wave: rows wq*16, cols wc*48
    const int m0 = blockIdx.x << 5;
    const int y  = blockIdx.y;

    // --- W-hi glds staging: 12 x 1KB per K-step, 3 per wave ---
    const unsigned short* gsrc[3];
    int gdst[3];
#pragma unroll
    for (int i = 0; i < 3; ++i) {
        int g = w * 3 + i;                      // 0..11
        int n = (g << 3) + (l >> 3);            // W row 0..95
        int cg = (l & 7) ^ ((l >> 3) & 7);      // swizzled source chunk
        gsrc[i] = Wthi + (size_t)(y * 96 + n) * 1024 + (cg << 3);
        gdst[i] = g << 9;
    }
    // --- X staging: thread -> 8 floats (row t>>3, chunk t&7) ---
    const int xr_ = t >> 3, xc_ = t & 7;
    const float* xptr = X + (size_t)(m0 + xr_) * 1024 + (xc_ << 3);
    const int xsl = ((xc_ ^ (xr_ & 7)) << 3);
    unsigned short* xwh = Xh + (xr_ << 6) + xsl;
    unsigned short* xwl = Xl + (xr_ << 6) + xsl;

    // --- fragment LDS offsets (slot = (kc*4+lg) ^ (row&7)) ---
    int aoff[2], boff[3][2];
#pragma unroll
    for (int kc = 0; kc < 2; ++kc)
        aoff[kc] = (((wq << 4) + lm) << 6) + ((((kc << 2) + lg) ^ (lm & 7)) << 3);
#pragma unroll
    for (int ct = 0; ct < 3; ++ct)
#pragma unroll
        for (int kc = 0; kc < 2; ++kc) {
            int n = wc * 48 + (ct << 4) + lm;
            boff[ct][kc] = (n << 6) + ((((kc << 2) + lg) ^ (lm & 7)) << 3);
        }
    // --- W-lo direct-global base (per-lane) ---
    const unsigned short* wlb = Wtlo + (size_t)(y * 96 + wc * 48 + lm) * 1024 + (lg << 3);

    f32x4 acc[3];
#pragma unroll
    for (int j = 0; j < 3; ++j) acc[j] = (f32x4){0.f, 0.f, 0.f, 0.f};

    // prologue
#pragma unroll
    for (int i = 0; i < 3; ++i) glds16(gsrc[i], Wh + gdst[i]);
    float4 xv0 = *(const float4*)xptr;
    float4 xv1 = *(const float4*)(xptr + 4);

    for (int k = 0; k < 16; ++k) {
        const int wb = (k & 1) * 6144;
        __syncthreads();                          // prev readers done
        if (k < 15) {
            const int ko = (k + 1) << 6;
            const int nb = 6144 - wb;
#pragma unroll
            for (int i = 0; i < 3; ++i) glds16(gsrc[i] + ko, Wh + nb + gdst[i]);
        }
        {   // trunc-split X(k) regs -> swizzled LDS
            float xf[8];
            xf[0] = xv0.x; xf[1] = xv0.y; xf[2] = xv0.z; xf[3] = xv0.w;
            xf[4] = xv1.x; xf[5] = xv1.y; xf[6] = xv1.z; xf[7] = xv1.w;
            us8 h, lo;
#pragma unroll
            for (int e = 0; e < 8; ++e) {
                unsigned u = __builtin_bit_cast(unsigned, xf[e]);
                h[e] = (unsigned short)(u >> 16);
                lo[e] = bftrunc(xf[e] - __builtin_bit_cast(float, u & 0xffff0000u));
            }
            *(us8*)xwh = h;
            *(us8*)xwl = lo;
        }
        __syncthreads();                          // stage + glds(cur buf) visible
        if (k < 15) {
            const int ko = (k + 1) << 6;
            xv0 = *(const float4*)(xptr + ko);
            xv1 = *(const float4*)(xptr + ko + 4);
        }
        us8 bl_[3][2];
#pragma unroll
        for (int ct = 0; ct < 3; ++ct)
#pragma unroll
            for (int kc = 0; kc < 2; ++kc)
                bl_[ct][kc] = *(const us8*)(wlb + ct * 16384 + (kc << 5) + (k << 6));
        us8 ah[2], al[2], bh[3][2];
#pragma unroll
        for (int kc = 0; kc < 2; ++kc) {
            ah[kc] = *(const us8*)&Xh[aoff[kc]];
            al[kc] = *(const us8*)&Xl[aoff[kc]];
        }
#pragma unroll
        for (int ct = 0; ct < 3; ++ct)
#pragma unroll
            for (int kc = 0; kc < 2; ++kc)
                bh[ct][kc] = *(const us8*)&Wh[wb + boff[ct][kc]];
        // LDS-fed terms first (hi*hi, lo*hi), W-lo global term last
#pragma unroll
        for (int kc = 0; kc < 2; ++kc)
#pragma unroll
            for (int ct = 0; ct < 3; ++ct) {
                acc[ct] = mfma16(ah[kc], bh[ct][kc], acc[ct]);
                acc[ct] = mfma16(al[kc], bh[ct][kc], acc[ct]);
            }
#pragma unroll
        for (int kc = 0; kc < 2; ++kc)
#pragma unroll
            for (int ct = 0; ct < 3; ++ct)
                acc[ct] = mfma16(ah[kc], bl_[ct][kc], acc[ct]);
    }

    // epilogue: trunc-split stores; Q pre-scaled; V transposed via Vx
    const int tbr = m0 + (wq << 4);
#pragma unroll
    for (int ct = 0; ct < 3; ++ct) {
        const int gc = y * 96 + wc * 48 + (ct << 4);
        if (gc < 128) {
            unsigned short* Dh = (gc < 64) ? Qhi : Khi;
            unsigned short* Dl = (gc < 64) ? Qlo : Klo;
            const float sc = (gc < 64) ? QSCALE : 1.0f;
            const int colb = (gc & 63) + lm;
#pragma unroll
            for (int r = 0; r < 4; ++r) {
                int row = tbr + (lg << 2) + r;
                float x = acc[ct][r] * sc;
                unsigned u = __builtin_bit_cast(unsigned, x);
                size_t o = (size_t)row * 64 + colb;
                Dh[o] = (unsigned short)(u >> 16);
                Dl[o] = bftrunc(x - __builtin_bit_cast(float, u & 0xffff0000u));
            }
        } else {
            // V: 16x16 transpose via wave-local LDS
#pragma unroll
            for (int r = 0; r < 4; ++r)
                Vx[w * 320 + lm * 20 + (lg << 2) + r] = bftrunc(acc[ct][r]);
            __asm__ volatile("" ::: "memory");
            const int h0 = gc - 128;
            const int tb = tbr;
            const int bb = tb >> 11;
            const int tl = (tb & 2047) + ((l & 3) << 2);
            const int hh2 = h0 + (l >> 2);
            us4 vv = *(const us4*)&Vx[w * 320 + (l >> 2) * 20 + ((l & 3) << 2)];
            *(us4*)&Vthi[(size_t)((bb << 6) + hh2) * 2048 + tl] = vv;
            __asm__ volatile("" ::: "memory");
        }
    }
}

// ---------------- Kernel 2: causal flash attention ----------------
// 512 blocks = (b, 32-row q-tile heavy-first). 4 waves = 4 key-parities,
// zero barriers in the K-loop. K/V frag loads chunked (mt-pairs / ct-pairs)
// to cut peak VGPR -> 3 waves/SIMD for latency hiding of softmax chains.
__global__ __launch_bounds__(256, 3) void attn_kernel(
    const unsigned short* __restrict__ Qhi, const unsigned short* __restrict__ Qlo,
    const unsigned short* __restrict__ Khi, const unsigned short* __restrict__ Klo,
    const unsigned short* __restrict__ Vthi,
    float* __restrict__ O)
{
    __shared__ __align__(16) unsigned char smem[33792];
    unsigned short* PS = (unsigned short*)smem;     // [4][32][72] us (loop phase)
    float* FO = (float*)smem;                       // [4][32][64] f32 (merge phase)
    float* FM = (float*)(smem + 32768);             // [4][32]
    float* FL = FM + 128;

    const int t = threadIdx.x;
    const int w = t >> 6, l = t & 63, lm = l & 15, lg = (l >> 4) & 3;
    const int b = blockIdx.x & 7;
    const int qp = 63 - (blockIdx.x >> 3);          // heavy tiles first
    const int nk = (qp >> 1) + 1;                   // 64-key tiles needed
    const int q0 = qp << 5;
    const size_t brow = (size_t)b << 11;

    // Q fragments pinned (B-operand: lane=qrow, k=lg*8+j)
    us8 qh[2][2], ql[2][2];
#pragma unroll
    for (int nt = 0; nt < 2; ++nt)
#pragma unroll
        for (int kc = 0; kc < 2; ++kc) {
            size_t off = (brow + q0 + (nt << 4) + lm) * 64 + (kc << 5) + (lg << 3);
            qh[nt][kc] = *(const us8*)&Qhi[off];
            ql[nt][kc] = *(const us8*)&Qlo[off];
        }

    f32x4 o_acc[2][4];
#pragma unroll
    for (int nt = 0; nt < 2; ++nt)
#pragma unroll
        for (int ct = 0; ct < 4; ++ct) o_acc[nt][ct] = (f32x4){0.f, 0.f, 0.f, 0.f};
    float m_r[2] = {NEG_INF, NEG_INF}, l_r[2] = {0.f, 0.f};
    unsigned short* ps = PS + w * 2304;             // wave-local 32x72

    for (int j = w; j < nk; j += 4) {
        const int kk0 = j << 6;
        f32x4 s[4][2];
#pragma unroll
        for (int mt = 0; mt < 4; ++mt)
#pragma unroll
            for (int nt = 0; nt < 2; ++nt) s[mt][nt] = (f32x4){0.f, 0.f, 0.f, 0.f};

        // ---- S^T = K Q^T in two mt-pair chunks (bounded live regs) ----
#pragma unroll
        for (int half = 0; half < 2; ++half) {
            us8 ka[2][2], kb[2][2];
#pragma unroll
            for (int mi = 0; mi < 2; ++mi)
#pragma unroll
                for (int kc = 0; kc < 2; ++kc) {
                    const int mt = (half << 1) + mi;
                    size_t off = (brow + kk0 + (mt << 4) + lm) * 64 + (kc << 5) + (lg << 3);
                    ka[mi][kc] = *(const us8*)&Khi[off];
                    kb[mi][kc] = *(const us8*)&Klo[off];
                }
#pragma unroll
            for (int kc = 0; kc < 2; ++kc)
#pragma unroll
                for (int mi = 0; mi < 2; ++mi)
#pragma unroll
                    for (int nt = 0; nt < 2; ++nt) {
                        const int mt = (half << 1) + mi;
                        s[mt][nt] = mfma16(ka[mi][kc], qh[nt][kc], s[mt][nt]);
                        s[mt][nt] = mfma16(kb[mi][kc], qh[nt][kc], s[mt][nt]);
                        s[mt][nt] = mfma16(ka[mi][kc], ql[nt][kc], s[mt][nt]);
                    }
        }

        // ---- online softmax (exp2 domain), lane owns row q0+nt*16+lm ----
        float alz[2];
#pragma unroll
        for (int nt = 0; nt < 2; ++nt) {
            const int qr = q0 + (nt << 4) + lm;
            float sv[16];
            if ((kk0 + 63) <= (q0 + (nt << 4))) {
#pragma unroll
                for (int mt = 0; mt < 4; ++mt)
#pragma unroll
                    for (int r = 0; r < 4; ++r) sv[(mt << 2) + r] = s[mt][nt][r];
            } else {
#pragma unroll
                for (int mt = 0; mt < 4; ++mt)
#pragma unroll
                    for (int r = 0; r < 4; ++r) {
                        const int key = kk0 + (mt << 4) + (lg << 2) + r;
                        sv[(mt << 2) + r] = (key <= qr) ? s[mt][nt][r] : NEG_INF;
                    }
            }
            float t8[8];
#pragma unroll
            for (int i = 0; i < 8; ++i) t8[i] = fmaxf(sv[i], sv[i + 8]);
#pragma unroll
            for (int i = 0; i < 4; ++i) t8[i] = fmaxf(t8[i], t8[i + 4]);
            float mx = fmaxf(fmaxf(t8[0], t8[1]), fmaxf(t8[2], t8[3]));
            mx = fmaxf(mx, __shfl_xor(mx, 16));
            mx = fmaxf(mx, __shfl_xor(mx, 32));
            const float mn = fmaxf(m_r[nt], mx);
            alz[nt] = fexp2(m_r[nt] - mn);
            m_r[nt] = mn;
            float p[16];
#pragma unroll
            for (int i = 0; i < 16; ++i) p[i] = fexp2(sv[i] - mn);
#pragma unroll
            for (int mt = 0; mt < 4; ++mt) {
                us4 pk;
#pragma unroll
                for (int r = 0; r < 4; ++r) pk[r] = bftrunc(p[(mt << 2) + r]);
                *(us4*)&ps[((nt << 4) + lm) * 72 + (mt << 4) + (lg << 2)] = pk;
            }
            float s8[8];
#pragma unroll
            for (int i = 0; i < 8; ++i) s8[i] = p[i] + p[i + 8];
#pragma unroll
            for (int i = 0; i < 4; ++i) s8[i] = s8[i] + s8[i + 4];
            float rs = (s8[0] + s8[1]) + (s8[2] + s8[3]);
            rs += __shfl_xor(rs, 16);
            rs += __shfl_xor(rs, 32);
            l_r[nt] = l_r[nt] * alz[nt] + rs;
        }
        __asm__ volatile("" ::: "memory");   // P write -> read, same wave
        // rescale O (alz lives at lane=row; fetch via shuffle)
#pragma unroll
        for (int nt = 0; nt < 2; ++nt)
#pragma unroll
            for (int r = 0; r < 4; ++r) {
                const float av = __shfl(alz[nt], (lg << 2) + r);
#pragma unroll
                for (int ct = 0; ct < 4; ++ct) o_acc[nt][ct][r] *= av;
            }
        // ---- O += P V in two ct-pair chunks ----
#pragma unroll
        for (int half = 0; half < 2; ++half) {
            us8 vh[2][2];
#pragma unroll
            for (int ci = 0; ci < 2; ++ci)
#pragma unroll
                for (int kc = 0; kc < 2; ++kc) {
                    const int ct = (half << 1) + ci;
                    size_t off = ((size_t)(b << 6) + (ct << 4) + lm) * 2048
                               + kk0 + (kc << 5) + (lg << 3);
                    vh[ci][kc] = *(const us8*)&Vthi[off];
                }
#pragma unroll
            for (int nt = 0; nt < 2; ++nt)
#pragma unroll
                for (int kc = 0; kc < 2; ++kc) {
                    us8 pa = *(const us8*)&ps[((nt << 4) + lm) * 72 + (kc << 5) + (lg << 3)];
#pragma unroll
                    for (int ci = 0; ci < 2; ++ci)
                        o_acc[nt][(half << 1) + ci] =
                            mfma16(pa, vh[ci][kc], o_acc[nt][(half << 1) + ci]);
                }
        }
    }

    // ---- 4-way key-parity merge ----
    __syncthreads();                         // all PS use done before FO alias
#pragma unroll
    for (int nt = 0; nt < 2; ++nt)
#pragma unroll
        for (int ct = 0; ct < 4; ++ct)
#pragma unroll
            for (int r = 0; r < 4; ++r)
                FO[(w << 11) + (((nt << 4) + (lg << 2) + r) << 6) + (ct << 4) + lm]
                    = o_acc[nt][ct][r];
    if (l < 16) {
        FM[(w << 5) + lm] = m_r[0]; FM[(w << 5) + 16 + lm] = m_r[1];
        FL[(w << 5) + lm] = l_r[0]; FL[(w << 5) + 16 + lm] = l_r[1];
    }
    __syncthreads();
    const int jr = t >> 3;                   // row 0..31
    const int cg = (t & 7) << 3;             // col base
    float m0v = FM[jr], m1v = FM[32 + jr], m2v = FM[64 + jr], m3v = FM[96 + jr];
    float mm = fmaxf(fmaxf(m0v, m1v), fmaxf(m2v, m3v));
    float a0 = fexp2(m0v - mm), a1 = fexp2(m1v - mm);
    float a2 = fexp2(m2v - mm), a3 = fexp2(m3v - mm);
    float L = a0 * FL[jr] + a1 * FL[32 + jr] + a2 * FL[64 + jr] + a3 * FL[96 + jr];
    float inv = 1.0f / L;
    float ov[8];
#pragma unroll
    for (int c = 0; c < 8; ++c)
        ov[c] = a0 * FO[(jr << 6) + cg + c] + a1 * FO[2048 + (jr << 6) + cg + c]
              + a2 * FO[4096 + (jr << 6) + cg + c] + a3 * FO[6144 + (jr << 6) + cg + c];
    float4 o1 = {ov[0] * inv, ov[1] * inv, ov[2] * inv, ov[3] * inv};
    float4 o2 = {ov[4] * inv, ov[5] * inv, ov[6] * inv, ov[7] * inv};
    float* op = O + (brow + q0 + jr) * 64 + cg;
    *(float4*)op = o1;
    *(float4*)(op + 4) = o2;
}

extern "C" void kernel_launch(void* const* d_in, const int* in_sizes, int n_in,
                              void* d_out, int out_size, void* d_ws, size_t ws_size,
                              hipStream_t stream) {
    const float* X  = (const float*)d_in[0];
    const float* Wq = (const float*)d_in[1];
    const float* Wk = (const float*)d_in[2];
    const float* Wv = (const float*)d_in[3];
    unsigned short* ws = (unsigned short*)d_ws;
    const size_t SZ = (size_t)16384 * 64;
    unsigned short* Qhi  = ws;
    unsigned short* Qlo  = ws + SZ;
    unsigned short* Khi  = ws + 2 * SZ;
    unsigned short* Klo  = ws + 3 * SZ;
    unsigned short* Vthi = ws + 4 * SZ;
    unsigned short* Wthi = ws + 5 * SZ;
    unsigned short* Wtlo = Wthi + 192 * 1024;

    wprep_kernel<<<48, 256, 0, stream>>>(Wq, Wk, Wv, Wthi, Wtlo);
    qkv_kernel<<<dim3(512, 2), 256, 0, stream>>>(X, Wthi, Wtlo,
                                                 Qhi, Qlo, Khi, Klo, Vthi);
    attn_kernel<<<512, 256, 0, stream>>>(Qhi, Qlo, Khi, Klo, Vthi, (float*)d_out);
}